// Round 2
// baseline (841.010 us; speedup 1.0000x reference)
//
#include <hip/hip_runtime.h>
#include <float.h>

// SOM2D argmin-distance, N=32768 samples, M=4096 units, D=128, fp32.
//
// Round-2 design: LDS-free main loop.
//  - One sample per LANE; its x[128] lives entirely in VGPRs (loaded once).
//  - One UNIT at a time per wave; w[u][*] is wave-uniform -> scalar (SGPR)
//    loads via uniformity from readfirstlane(wave id). v_fma_f32 v,v,s,v
//    reads the SGPR operand for free -> zero LDS bandwidth in the hot loop.
//  - Block = 4 waves x 64 lanes sharing the same 64 samples; each wave scans
//    a disjoint quarter of the units. Tiny LDS epilogue combines the 4
//    partial argmins.
// Floor: 268M v_fma_f32 wave-instrs * 2cyc / 1024 SIMDs = 218 us @ 2.4 GHz.

constexpr int D   = 128;
constexpr int SPB = 64;   // samples per block (one per lane)
constexpr int NW  = 4;    // waves per block

// ||w||^2 per unit -> d_ws
__global__ void wsq_kernel(const float* __restrict__ w, float* __restrict__ wsq, int M) {
    int u = blockIdx.x * blockDim.x + threadIdx.x;
    if (u >= M) return;
    const float4* wp = reinterpret_cast<const float4*>(w + (size_t)u * D);
    float a0 = 0.f, a1 = 0.f, a2 = 0.f, a3 = 0.f;
#pragma unroll
    for (int k = 0; k < D / 4; ++k) {
        float4 v = wp[k];
        a0 = fmaf(v.x, v.x, a0); a1 = fmaf(v.y, v.y, a1);
        a2 = fmaf(v.z, v.z, a2); a3 = fmaf(v.w, v.w, a3);
    }
    wsq[u] = (a0 + a1) + (a2 + a3);
}

__global__ __launch_bounds__(256) void som_kernel(
        const float* __restrict__ x, const float* __restrict__ w,
        const float* __restrict__ wsq, const int* __restrict__ grid,
        int* __restrict__ out, int M) {
    const int t    = threadIdx.x;
    const int lane = t & 63;
    // Force wave id uniform so every derived unit index is provably
    // wave-uniform -> W loads select the scalar (SMEM) path.
    const int wv   = __builtin_amdgcn_readfirstlane(t >> 6);
    const int sBase = blockIdx.x * SPB;
    const int s     = sBase + lane;

    // ---- load this lane's sample into registers (one-time; all 4 waves read
    // the same 64 rows, so waves 1-3 hit L1) ----
    float xr[D];
    {
        const float4* xg = reinterpret_cast<const float4*>(x + (size_t)s * D);
#pragma unroll
        for (int c = 0; c < D / 4; ++c) {
            float4 v = xg[c];
            xr[4 * c + 0] = v.x; xr[4 * c + 1] = v.y;
            xr[4 * c + 2] = v.z; xr[4 * c + 3] = v.w;
        }
    }

    // ||x||^2 (4 independent chains)
    float xq;
    {
        float a0 = 0.f, a1 = 0.f, a2 = 0.f, a3 = 0.f;
#pragma unroll
        for (int k = 0; k < D; k += 4) {
            a0 = fmaf(xr[k + 0], xr[k + 0], a0);
            a1 = fmaf(xr[k + 1], xr[k + 1], a1);
            a2 = fmaf(xr[k + 2], xr[k + 2], a2);
            a3 = fmaf(xr[k + 3], xr[k + 3], a3);
        }
        xq = (a0 + a1) + (a2 + a3);
    }

    // ---- scan this wave's quarter of the units, two at a time ----
    const int uPer = M / NW;          // 1024
    const int u0   = wv * uPer;

    float bestD = FLT_MAX;
    int   bestI = 0;

    for (int u = u0; u < u0 + uPer; u += 2) {
        const float* wa = w + (size_t)u * D;        // wave-uniform addresses
        const float* wb = wa + D;
        float a0 = 0.f, a1 = 0.f, a2 = 0.f, a3 = 0.f;   // unit u
        float b0 = 0.f, b1 = 0.f, b2 = 0.f, b3 = 0.f;   // unit u+1
#pragma unroll
        for (int k = 0; k < D; k += 4) {
            a0 = fmaf(xr[k + 0], wa[k + 0], a0);
            a1 = fmaf(xr[k + 1], wa[k + 1], a1);
            a2 = fmaf(xr[k + 2], wa[k + 2], a2);
            a3 = fmaf(xr[k + 3], wa[k + 3], a3);
            b0 = fmaf(xr[k + 0], wb[k + 0], b0);
            b1 = fmaf(xr[k + 1], wb[k + 1], b1);
            b2 = fmaf(xr[k + 2], wb[k + 2], b2);
            b3 = fmaf(xr[k + 3], wb[k + 3], b3);
        }
        const float dotA = (a0 + a1) + (a2 + a3);
        const float dotB = (b0 + b1) + (b2 + b3);
        const float wqA  = wsq[u];                  // uniform -> s_load
        const float wqB  = wsq[u + 1];
        const float scoreA = (xq + wqA) - 2.f * dotA;
        const float scoreB = (xq + wqB) - 2.f * dotB;
        // ascending u -> strict < keeps the lowest index on ties
        if (scoreA < bestD) { bestD = scoreA; bestI = u; }
        if (scoreB < bestD) { bestD = scoreB; bestI = u + 1; }
    }

    // ---- combine the 4 wave-partials (each wave covers an ascending,
    // disjoint index range; later waves have strictly larger indices, so
    // strict < preserves lowest-index tie-breaking) ----
    __shared__ float rd[NW][SPB];
    __shared__ int   ri[NW][SPB];
    rd[wv][lane] = bestD;
    ri[wv][lane] = bestI;
    __syncthreads();
    if (t < SPB) {
        float bd = rd[0][t];
        int   bi = ri[0][t];
#pragma unroll
        for (int k = 1; k < NW; ++k) {
            float dk = rd[k][t];
            int   ik = ri[k][t];
            if (dk < bd) { bd = dk; bi = ik; }
        }
        const int so = sBase + t;
        out[2 * so]     = grid[2 * bi];
        out[2 * so + 1] = grid[2 * bi + 1];
    }
}

extern "C" void kernel_launch(void* const* d_in, const int* in_sizes, int n_in,
                              void* d_out, int out_size, void* d_ws, size_t ws_size,
                              hipStream_t stream) {
    const float* x    = (const float*)d_in[0];
    const float* w    = (const float*)d_in[1];
    const int*   grid = (const int*)d_in[2];
    int* out = (int*)d_out;

    const int N = in_sizes[0] / D;   // 32768
    const int M = in_sizes[1] / D;   // 4096
    float* wsq = (float*)d_ws;       // M floats of scratch

    wsq_kernel<<<(M + 255) / 256, 256, 0, stream>>>(w, wsq, M);
    som_kernel<<<N / SPB, 256, 0, stream>>>(x, w, wsq, grid, out, M);
}

// Round 3
// 190.957 us; speedup vs baseline: 4.4042x; 4.4042x over previous
//
#include <hip/hip_runtime.h>
#include <float.h>
#include <stdint.h>

// SOM2D argmin ||x-w||^2 via split-f16 MFMA. N=32768, M=4096, D=128.
//
// argmin_u (||x||^2 + ||w||^2 - 2 x.w) == argmin_u (||w||^2 - 2 x.w): drop xq.
// cross = xh*wh + xh*wl + xl*wh (f16 hi/lo split, fp32 MFMA accum).
// Error ~2e-5 absolute on dist -- far below observed winner margins.
//
// Per wave: A-frags (64 samples x K=128, h+l) resident in 128 VGPRs; only W
// tiles (64 units) stream through LDS as f16 frag-major (read = base+lane*16,
// conflict-free). 512 blocks = 128 sample-groups x 4 unit-groups = 2 blocks/CU;
// cross-block combine via atomicMin on packed (distbits,idx) u64 keys in ws.

constexpr int D = 128;

typedef _Float16 f16x8 __attribute__((ext_vector_type(8)));
typedef float    f32x4 __attribute__((ext_vector_type(4)));

__global__ void wsq_kernel(const float* __restrict__ w, float* __restrict__ wsq, int M) {
    int u = blockIdx.x * blockDim.x + threadIdx.x;
    if (u >= M) return;
    const float4* wp = reinterpret_cast<const float4*>(w + (size_t)u * D);
    float a0 = 0.f, a1 = 0.f, a2 = 0.f, a3 = 0.f;
#pragma unroll
    for (int k = 0; k < D / 4; ++k) {
        float4 v = wp[k];
        a0 = fmaf(v.x, v.x, a0); a1 = fmaf(v.y, v.y, a1);
        a2 = fmaf(v.z, v.z, a2); a3 = fmaf(v.w, v.w, a3);
    }
    wsq[u] = (a0 + a1) + (a2 + a3);
}

__global__ void keys_init(unsigned long long* __restrict__ keys, int N) {
    int i = blockIdx.x * blockDim.x + threadIdx.x;
    if (i < N) keys[i] = ~0ull;
}

__global__ void finalize(const unsigned long long* __restrict__ keys,
                         const int* __restrict__ grid, int* __restrict__ out, int N) {
    int s = blockIdx.x * blockDim.x + threadIdx.x;
    if (s >= N) return;
    int idx = (int)(unsigned)(keys[s] & 0xFFFFFFFFull);
    out[2 * s]     = grid[2 * idx];
    out[2 * s + 1] = grid[2 * idx + 1];
}

__device__ __forceinline__ void cvt_split(const float4& a0, const float4& a1,
                                          f16x8& h, f16x8& l) {
    float v[8] = {a0.x, a0.y, a0.z, a0.w, a1.x, a1.y, a1.z, a1.w};
#pragma unroll
    for (int j = 0; j < 8; ++j) {
        _Float16 hh = (_Float16)v[j];
        h[j] = hh;
        l[j] = (_Float16)(v[j] - (float)hh);
    }
}

template <bool ATOMIC>
__global__ __launch_bounds__(256, 2) void som_mfma(
        const float* __restrict__ x, const float* __restrict__ w,
        const float* __restrict__ wsq, const int* __restrict__ grid,
        int* __restrict__ out, unsigned long long* __restrict__ keys,
        int unitGroups, int M) {
    // frag-major W tile: slot index = (kstep*4 + ntile)*64 + lane
    __shared__ f16x8 hbuf[1024];   // 16 KB
    __shared__ f16x8 lbuf[1024];   // 16 KB

    const int tid  = threadIdx.x;
    const int lane = tid & 63;
    const int wv   = tid >> 6;        // wave 0..3 (stacks the m dimension)
    const int c    = lane & 15;       // col-class within frag
    const int q    = lane >> 4;       // quad

    const int ug       = blockIdx.x % unitGroups;
    const int sg       = blockIdx.x / unitGroups;
    const int sBase    = sg * 256 + wv * 64;       // this wave's 64 samples
    const int unitsPer = M / unitGroups;
    const int uStart   = ug * unitsPer;
    const int nTiles   = unitsPer / 64;

    // ---- one-time: A-frags for 64 samples x K=128, h+l, resident in VGPRs.
    // A layout (16x16x32): A[m = lane&15][k = q*8 + j], m-tile i, kstep s.
    f16x8 Ah[16], Al[16];
#pragma unroll
    for (int i = 0; i < 4; ++i) {
        const float* xr = x + (size_t)(sBase + 16 * i + c) * D + q * 8;
#pragma unroll
        for (int s = 0; s < 4; ++s) {
            float4 a0 = *reinterpret_cast<const float4*>(xr + 32 * s);
            float4 a1 = *reinterpret_cast<const float4*>(xr + 32 * s + 4);
            cvt_split(a0, a1, Ah[i * 4 + s], Al[i * 4 + s]);
        }
    }

    float bestD[16];
    int   bestI[16];
#pragma unroll
    for (int sl = 0; sl < 16; ++sl) { bestD[sl] = FLT_MAX; bestI[sl] = 0; }

    for (int tile = 0; tile < nTiles; ++tile) {
        const int uTile = uStart + tile * 64;
        __syncthreads();
        // ---- stage W tile: 64 units x 128 k, fp32 -> f16 h/l, frag-major ----
#pragma unroll
        for (int it = 0; it < 4; ++it) {
            int p   = tid + 256 * it;   // pair index: 64 rows x 16 pairs
            int row = p & 63;
            int cp  = p >> 6;           // k-pair 0..15 (k = 8*cp..8*cp+7)
            const float* wp = w + (size_t)(uTile + row) * D + cp * 8;
            float4 b0 = *reinterpret_cast<const float4*>(wp);
            float4 b1 = *reinterpret_cast<const float4*>(wp + 4);
            f16x8 h, l;
            cvt_split(b0, b1, h, l);
            // slot = (s*4 + t)*64 + quad*16 + n ; s=cp>>2, quad=cp&3, t=row>>4, n=row&15
            int slot = ((cp >> 2) * 4 + (row >> 4)) * 64 + (cp & 3) * 16 + (row & 15);
            hbuf[slot] = h;
            lbuf[slot] = l;
        }
        __syncthreads();

        f32x4 acc[16];
#pragma unroll
        for (int f = 0; f < 16; ++f) acc[f] = (f32x4){0.f, 0.f, 0.f, 0.f};

#pragma unroll
        for (int s = 0; s < 4; ++s) {
            f16x8 bf[4];
#pragma unroll
            for (int t = 0; t < 4; ++t) bf[t] = hbuf[(s * 4 + t) * 64 + lane];
            // pass 1: xh . wh
#pragma unroll
            for (int i = 0; i < 4; ++i)
#pragma unroll
                for (int t = 0; t < 4; ++t)
                    acc[i * 4 + t] = __builtin_amdgcn_mfma_f32_16x16x32_f16(
                        Ah[i * 4 + s], bf[t], acc[i * 4 + t], 0, 0, 0);
            // pass 2: xl . wh
#pragma unroll
            for (int i = 0; i < 4; ++i)
#pragma unroll
                for (int t = 0; t < 4; ++t)
                    acc[i * 4 + t] = __builtin_amdgcn_mfma_f32_16x16x32_f16(
                        Al[i * 4 + s], bf[t], acc[i * 4 + t], 0, 0, 0);
            // pass 3: xh . wl
#pragma unroll
            for (int t = 0; t < 4; ++t) bf[t] = lbuf[(s * 4 + t) * 64 + lane];
#pragma unroll
            for (int i = 0; i < 4; ++i)
#pragma unroll
                for (int t = 0; t < 4; ++t)
                    acc[i * 4 + t] = __builtin_amdgcn_mfma_f32_16x16x32_f16(
                        Ah[i * 4 + s], bf[t], acc[i * 4 + t], 0, 0, 0);
        }

        // ---- score + running per-lane argmin. C layout: row m = q*4+reg (+16i),
        // col n = c (+16t). t ascending => lowest index wins on ties. ----
#pragma unroll
        for (int t = 0; t < 4; ++t) {
            const int n   = uTile + 16 * t + c;
            const float wq = wsq[n];
#pragma unroll
            for (int i = 0; i < 4; ++i) {
                f32x4 a = acc[i * 4 + t];
#pragma unroll
                for (int r = 0; r < 4; ++r) {
                    float score = fmaf(-2.f, a[r], wq);
                    int sl = i * 4 + r;
                    if (score < bestD[sl]) { bestD[sl] = score; bestI[sl] = n; }
                }
            }
        }
    }

    // ---- cross-lane reduce over the 16 col-classes (xor within quarter) ----
#pragma unroll
    for (int sl = 0; sl < 16; ++sl) {
        float d   = bestD[sl];
        int   idx = bestI[sl];
#pragma unroll
        for (int m = 1; m < 16; m <<= 1) {
            float od = __shfl_xor(d, m, 64);
            int   oi = __shfl_xor(idx, m, 64);
            if (od < d || (od == d && oi < idx)) { d = od; idx = oi; }
        }
        if (c == 0) {
            const int sOut = sBase + 16 * (sl >> 2) + 4 * q + (sl & 3);
            if (ATOMIC) {
                unsigned ub = __float_as_uint(d);
                ub = (ub & 0x80000000u) ? ~ub : (ub | 0x80000000u);  // monotone map
                unsigned long long key = ((unsigned long long)ub << 32) | (unsigned)idx;
                atomicMin(&keys[sOut], key);
            } else {
                out[2 * sOut]     = grid[2 * idx];
                out[2 * sOut + 1] = grid[2 * idx + 1];
            }
        }
    }
}

extern "C" void kernel_launch(void* const* d_in, const int* in_sizes, int n_in,
                              void* d_out, int out_size, void* d_ws, size_t ws_size,
                              hipStream_t stream) {
    const float* x    = (const float*)d_in[0];
    const float* w    = (const float*)d_in[1];
    const int*   grid = (const int*)d_in[2];
    int* out = (int*)d_out;

    const int N = in_sizes[0] / D;   // 32768
    const int M = in_sizes[1] / D;   // 4096

    const size_t keysBytes = (size_t)N * 8;
    const bool bigWs = ws_size >= keysBytes + (size_t)M * 4;

    if (bigWs) {
        unsigned long long* keys = (unsigned long long*)d_ws;
        float* wsq = (float*)((char*)d_ws + keysBytes);
        keys_init<<<(N + 255) / 256, 256, 0, stream>>>(keys, N);
        wsq_kernel<<<(M + 255) / 256, 256, 0, stream>>>(w, wsq, M);
        const int UG = 4;  // 128 sample-groups x 4 unit-groups = 512 blocks = 2/CU
        som_mfma<true><<<(N / 256) * UG, 256, 0, stream>>>(
            x, w, wsq, grid, out, keys, UG, M);
        finalize<<<(N + 255) / 256, 256, 0, stream>>>(keys, grid, out, N);
    } else {
        float* wsq = (float*)d_ws;   // proven to fit (round 1 used M floats)
        wsq_kernel<<<(M + 255) / 256, 256, 0, stream>>>(w, wsq, M);
        som_mfma<false><<<N / 256, 256, 0, stream>>>(
            x, w, wsq, grid, out, nullptr, 1, M);
    }
}